// Round 5
// baseline (556.762 us; speedup 1.0000x reference)
//
#include <hip/hip_runtime.h>

// B=8,C=3,H=1024,W=1024 f32 circular-roll stencil.
// Round 5: identical to round-3/4 (two GPU acquisition timeouts; untested).
// 2 rows x 8 cols per thread, XCD-chunked swizzle, NT loads for zero-reuse
// inputs + NT stores for outputs, via clang ext_vector_type (HIP_vector_type
// struct is rejected by __builtin_nontemporal_*).

#define HH 1024
#define WW 1024
#define NP 24                      // B*C planes
#define NBLOCKS (NP * HH / 4)      // 4 rows per block -> 6144 (divisible by 8)

typedef float f4 __attribute__((ext_vector_type(4)));

#define FILL8(dst, va, vb) \
    { (dst)[0]=(va).x; (dst)[1]=(va).y; (dst)[2]=(va).z; (dst)[3]=(va).w; \
      (dst)[4]=(vb).x; (dst)[5]=(vb).y; (dst)[6]=(vb).z; (dst)[7]=(vb).w; }

__global__ __launch_bounds__(256) void rmodule_kernel(
    const float* __restrict__ diagAtA,
    const float* __restrict__ Aty,
    const float* __restrict__ mk,
    const float* __restrict__ lambdak,
    const float* __restrict__ gamma_n_p,
    const float* __restrict__ gamma_p_p,
    const int*   __restrict__ scale_p,
    float* __restrict__ out_m_r,
    float* __restrict__ out_invSigma)
{
    // XCD-chunked bijective swizzle: physical block b -> XCD b%8 (round-robin
    // dispatch); give each XCD a contiguous range of logical row-pair chunks.
    const int b  = blockIdx.x;
    const int lb = (b & 7) * (NBLOCKS / 8) + (b >> 3);

    const int t    = threadIdx.x;
    const int rp   = lb * 2 + (t >> 7);    // global row-pair id [0, 12288)
    const int lane = t & 127;              // 128 threads cover one row-pair
    const int w0   = lane << 3;            // 8 floats per thread in w

    const int plane = rp >> 9;             // 512 row-pairs per plane
    const int h0  = (rp & 511) << 1;
    const int h1  = h0 + 1;
    const int hm1 = (h0 == 0)      ? (HH - 1) : (h0 - 1);
    const int h2  = (h1 == HH - 1) ? 0        : (h1 + 1);

    const int base = plane * (HH * WW);
    const float* __restrict__ mkp = mk + base;
    const float* __restrict__ lmp = lambdak + base;

    const int rm1 = hm1 * WW, r0 = h0 * WW, r1 = h1 * WW, r2 = h2 * WW;

    const float gn = gamma_n_p[0];
    const float gp = gamma_p_p[0];
    const int scale = scale_p[0];

    #define LD4(p)  (*reinterpret_cast<const f4*>(p))
    #define LDNT(p) (__builtin_nontemporal_load(reinterpret_cast<const f4*>(p)))
    #define STNT(v, p) __builtin_nontemporal_store((v), reinterpret_cast<f4*>(p))

    // mk: 4 rows (hm1,h0,h1,h2) -- cached (halo reuse across blocks)
    const f4 Mm1a = LD4(mkp + rm1 + w0), Mm1b = LD4(mkp + rm1 + w0 + 4);
    const f4 M0a  = LD4(mkp + r0  + w0), M0b  = LD4(mkp + r0  + w0 + 4);
    const f4 M1a  = LD4(mkp + r1  + w0), M1b  = LD4(mkp + r1  + w0 + 4);
    const f4 M2a  = LD4(mkp + r2  + w0), M2b  = LD4(mkp + r2  + w0 + 4);
    // lambdak: 3 rows (h0,h1,h2) -- cached
    const f4 L0a  = LD4(lmp + r0  + w0), L0b  = LD4(lmp + r0  + w0 + 4);
    const f4 L1a  = LD4(lmp + r1  + w0), L1b  = LD4(lmp + r1  + w0 + 4);
    const f4 L2a  = LD4(lmp + r2  + w0), L2b  = LD4(lmp + r2  + w0 + 4);
    // diagAtA, Aty: zero reuse -> nontemporal
    const f4 A0a = LDNT(diagAtA + base + r0 + w0);
    const f4 A0b = LDNT(diagAtA + base + r0 + w0 + 4);
    const f4 A1a = LDNT(diagAtA + base + r1 + w0);
    const f4 A1b = LDNT(diagAtA + base + r1 + w0 + 4);
    const f4 Y0a = LDNT(Aty     + base + r0 + w0);
    const f4 Y0b = LDNT(Aty     + base + r0 + w0 + 4);
    const f4 Y1a = LDNT(Aty     + base + r1 + w0);
    const f4 Y1b = LDNT(Aty     + base + r1 + w0 + 4);

    // circular w halos (scalar; mostly L1/L2 hits)
    const int wR = (w0 + 8) & (WW - 1);
    const int wL = (w0 - 1) & (WW - 1);
    const float m0l = mkp[r0 + wL], m0r = mkp[r0 + wR];
    const float m1l = mkp[r1 + wL], m1r = mkp[r1 + wR];
    const float l0r = lmp[r0 + wR], l1r = lmp[r1 + wR];

    const int rw_init = w0 % scale;

    // ---------------- row 0 ----------------
    {
        float lamR[9]; FILL8(lamR, L0a, L0b); lamR[8] = l0r;
        float lamS[8]; FILL8(lamS, L1a, L1b);
        float mC[10];  mC[0] = m0l; FILL8((mC + 1), M0a, M0b); mC[9] = m0r;
        float mN[8];   FILL8(mN, Mm1a, Mm1b);
        float mS[8];   FILL8(mS, M1a, M1b);
        float av[8];   FILL8(av, A0a, A0b);
        float yv[8];   FILL8(yv, Y0a, Y0b);

        const bool hOn = (h0 % scale) == 0;
        int rw = rw_init;
        float om[8], os[8];
#pragma unroll
        for (int i = 0; i < 8; ++i) {
            const float lam_c = lamR[i], lam_e = lamR[i + 1], lam_s = lamS[i];
            const float m_c = mC[i + 1], m_w = mC[i], m_e = mC[i + 2];
            const float m_n = mN[i], m_s = mS[i];
            const float diagD = 2.0f * lam_c + lam_e + lam_s;
            const float is = fmaxf(gn * av[i] + gp * diagD, 0.0f) + 0.0001f;
            const float atamk = (hOn && rw == 0) ? m_c : 0.0f;
            rw++; if (rw == scale) rw = 0;
            const float dh = lam_c * (m_c - m_w) - lam_e * (m_e - m_c);
            const float dv = lam_c * (m_c - m_n) - lam_s * (m_s - m_c);
            const float num = gn * (yv[i] - atamk + av[i] * m_c)
                            - gp * (dh + dv) + gp * diagD * m_c;
            om[i] = num / is;
            os[i] = is;
        }
        f4 v;
        v.x = om[0]; v.y = om[1]; v.z = om[2]; v.w = om[3];
        STNT(v, out_m_r + base + r0 + w0);
        v.x = om[4]; v.y = om[5]; v.z = om[6]; v.w = om[7];
        STNT(v, out_m_r + base + r0 + w0 + 4);
        v.x = os[0]; v.y = os[1]; v.z = os[2]; v.w = os[3];
        STNT(v, out_invSigma + base + r0 + w0);
        v.x = os[4]; v.y = os[5]; v.z = os[6]; v.w = os[7];
        STNT(v, out_invSigma + base + r0 + w0 + 4);
    }

    // ---------------- row 1 ----------------
    {
        float lamR[9]; FILL8(lamR, L1a, L1b); lamR[8] = l1r;
        float lamS[8]; FILL8(lamS, L2a, L2b);
        float mC[10];  mC[0] = m1l; FILL8((mC + 1), M1a, M1b); mC[9] = m1r;
        float mN[8];   FILL8(mN, M0a, M0b);
        float mS[8];   FILL8(mS, M2a, M2b);
        float av[8];   FILL8(av, A1a, A1b);
        float yv[8];   FILL8(yv, Y1a, Y1b);

        const bool hOn = (h1 % scale) == 0;
        int rw = rw_init;
        float om[8], os[8];
#pragma unroll
        for (int i = 0; i < 8; ++i) {
            const float lam_c = lamR[i], lam_e = lamR[i + 1], lam_s = lamS[i];
            const float m_c = mC[i + 1], m_w = mC[i], m_e = mC[i + 2];
            const float m_n = mN[i], m_s = mS[i];
            const float diagD = 2.0f * lam_c + lam_e + lam_s;
            const float is = fmaxf(gn * av[i] + gp * diagD, 0.0f) + 0.0001f;
            const float atamk = (hOn && rw == 0) ? m_c : 0.0f;
            rw++; if (rw == scale) rw = 0;
            const float dh = lam_c * (m_c - m_w) - lam_e * (m_e - m_c);
            const float dv = lam_c * (m_c - m_n) - lam_s * (m_s - m_c);
            const float num = gn * (yv[i] - atamk + av[i] * m_c)
                            - gp * (dh + dv) + gp * diagD * m_c;
            om[i] = num / is;
            os[i] = is;
        }
        f4 v;
        v.x = om[0]; v.y = om[1]; v.z = om[2]; v.w = om[3];
        STNT(v, out_m_r + base + r1 + w0);
        v.x = om[4]; v.y = om[5]; v.z = om[6]; v.w = om[7];
        STNT(v, out_m_r + base + r1 + w0 + 4);
        v.x = os[0]; v.y = os[1]; v.z = os[2]; v.w = os[3];
        STNT(v, out_invSigma + base + r1 + w0);
        v.x = os[4]; v.y = os[5]; v.z = os[6]; v.w = os[7];
        STNT(v, out_invSigma + base + r1 + w0 + 4);
    }
}

extern "C" void kernel_launch(void* const* d_in, const int* in_sizes, int n_in,
                              void* d_out, int out_size, void* d_ws, size_t ws_size,
                              hipStream_t stream) {
    const float* diagAtA = (const float*)d_in[0];
    const float* Aty     = (const float*)d_in[1];
    const float* mk      = (const float*)d_in[2];
    const float* lambdak = (const float*)d_in[3];
    const float* gamma_n = (const float*)d_in[4];
    const float* gamma_p = (const float*)d_in[5];
    const int*   scale   = (const int*)d_in[6];

    float* out = (float*)d_out;
    const int n = out_size / 2;             // 8*3*1024*1024
    rmodule_kernel<<<NBLOCKS, 256, 0, stream>>>(
        diagAtA, Aty, mk, lambdak, gamma_n, gamma_p, scale,
        out, out + n);
}